// Round 1
// baseline (544.835 us; speedup 1.0000x reference)
//
#include <hip/hip_runtime.h>
#include <hip/hip_bf16.h>

typedef unsigned short u16;
typedef __bf16 bf16x8 __attribute__((ext_vector_type(8)));
typedef float f32x4 __attribute__((ext_vector_type(4)));
typedef unsigned short u16x4 __attribute__((ext_vector_type(4)));

#define MFMA16(a, b, c) __builtin_amdgcn_mfma_f32_16x16x32_bf16(a, b, c, 0, 0, 0)

__device__ __forceinline__ u16 f2bf(float f) {
  union { float f; unsigned u; } v; v.f = f;
  unsigned r = v.u + 0x7FFFu + ((v.u >> 16) & 1u);
  return (u16)(r >> 16);
}

__device__ __forceinline__ void gload16(const u16* g, u16* l) {
  __builtin_amdgcn_global_load_lds(
      (const __attribute__((address_space(1))) unsigned int*)g,
      (__attribute__((address_space(3))) unsigned int*)l, 16, 0, 0);
}

// ---------------- elementwise f32 -> bf16 ----------------
__global__ void cvt_x(const float* __restrict__ X, u16* __restrict__ Xb, int n4) {
  int i = blockIdx.x * blockDim.x + threadIdx.x;
  if (i < n4) {
    float4 v = ((const float4*)X)[i];
    u16x4 o = { f2bf(v.x), f2bf(v.y), f2bf(v.z), f2bf(v.w) };
    ((u16x4*)Xb)[i] = o;
  }
}

// ---------------- tiled transpose + convert: W[K][N] f32 -> WT[N][K] bf16 ----------------
__global__ void transpose_cvt(const float* __restrict__ W, u16* __restrict__ WT, int K, int N) {
  __shared__ float t[32][33];
  int n0 = blockIdx.x * 32, k0 = blockIdx.y * 32;
  int tx = threadIdx.x, ty = threadIdx.y;
  t[ty][tx] = W[(size_t)(k0 + ty) * N + n0 + tx];
  __syncthreads();
  WT[(size_t)(n0 + ty) * K + k0 + tx] = f2bf(t[tx][ty]);
}

// ---------------- GEMM: C[M][N] = A[M][K] @ BT[N][K]^T (bf16 in, f32 acc) ----------------
// STORE: 0 = bf16 row-major [M][N], 1 = bf16 transposed [N][M], 2 = f32 row-major [M][N]
template <int STORE>
__global__ __launch_bounds__(256) void gemm_bt(const u16* __restrict__ A,
                                               const u16* __restrict__ BT,
                                               void* __restrict__ Cv,
                                               int M, int N, int K) {
  __shared__ u16 lA[128 * 32];
  __shared__ u16 lB[128 * 32];
  const int tid = threadIdx.x;
  const int lane = tid & 63;
  const int wave = tid >> 6;
  const int wm = (wave >> 1) * 64, wn = (wave & 1) * 64;
  const int bm = blockIdx.y * 128, bn = blockIdx.x * 128;
  const int l15 = lane & 15, l4 = lane >> 4;

  f32x4 acc[4][4] = {};

  for (int k0 = 0; k0 < K; k0 += 32) {
    __syncthreads();
#pragma unroll
    for (int it = 0; it < 2; ++it) {
      int s = it * 256 + tid;
      int row = s >> 2, pkb = s & 3;
      int kb = pkb ^ ((row >> 1) & 3);  // pre-swizzled global source (both-sides rule)
      gload16(A + (size_t)(bm + row) * K + k0 + kb * 8, &lA[s * 8]);
      gload16(BT + (size_t)(bn + row) * K + k0 + kb * 8, &lB[s * 8]);
    }
    __syncthreads();
    bf16x8 af[4], bf[4];
#pragma unroll
    for (int i = 0; i < 4; ++i) {
      int r = wm + i * 16 + l15;
      int pk = l4 ^ ((r >> 1) & 3);
      af[i] = *(const bf16x8*)&lA[r * 32 + pk * 8];
      int n = wn + i * 16 + l15;
      int pkn = l4 ^ ((n >> 1) & 3);
      bf[i] = *(const bf16x8*)&lB[n * 32 + pkn * 8];
    }
#pragma unroll
    for (int i = 0; i < 4; ++i)
#pragma unroll
      for (int j = 0; j < 4; ++j)
        acc[i][j] = MFMA16(af[i], bf[j], acc[i][j]);
  }

#pragma unroll
  for (int i = 0; i < 4; ++i) {
    int row = bm + wm + i * 16 + l4 * 4;
#pragma unroll
    for (int j = 0; j < 4; ++j) {
      int col = bn + wn + j * 16 + l15;
#pragma unroll
      for (int e = 0; e < 4; ++e) {
        float v = acc[i][j][e];
        if (STORE == 0)      ((u16*)Cv)[(size_t)(row + e) * N + col] = f2bf(v);
        else if (STORE == 1) ((u16*)Cv)[(size_t)col * M + (row + e)] = f2bf(v);
        else                 ((float*)Cv)[(size_t)(row + e) * N + col] = v;
      }
    }
  }
}

// ---------------- causal flash attention ----------------
// Q: [B*S][2048] bf16 (col = h*64+d), K: [B*S][512] bf16 (col = g*64+d),
// VT: [512][B*S] bf16 (row = g*64+d), AO: [B*S][2048] bf16
// grid (S/16, H, B), block = 1 wave. head h uses group g = h % 8.
__global__ __launch_bounds__(64) void attn_fwd(const u16* __restrict__ Q,
                                               const u16* __restrict__ Kb,
                                               const u16* __restrict__ VT,
                                               u16* __restrict__ AO) {
  const int qb = blockIdx.x, h = blockIdx.y, b = blockIdx.z;
  const int g = h & 7;
  const int lane = threadIdx.x;
  const int l15 = lane & 15, l4 = lane >> 4;
  const int q0 = qb * 16;
  __shared__ u16 P[16 * 64];

  const u16* qp = Q + (size_t)(b * 2048 + q0 + l15) * 2048 + h * 64 + l4 * 8;
  bf16x8 qf0 = *(const bf16x8*)qp;
  bf16x8 qf1 = *(const bf16x8*)(qp + 32);

  float m_r[4], l_r[4];
  f32x4 o[4] = {};
#pragma unroll
  for (int j = 0; j < 4; ++j) { m_r[j] = -1e30f; l_r[j] = 0.f; }

  for (int t0 = 0; t0 <= q0; t0 += 64) {
    f32x4 s[4];
#pragma unroll
    for (int ct = 0; ct < 4; ++ct) {
      const u16* kp = Kb + (size_t)(b * 2048 + t0 + ct * 16 + l15) * 512 + g * 64 + l4 * 8;
      bf16x8 kf0 = *(const bf16x8*)kp;
      bf16x8 kf1 = *(const bf16x8*)(kp + 32);
      f32x4 sv = {0.f, 0.f, 0.f, 0.f};
      sv = MFMA16(qf0, kf0, sv);
      sv = MFMA16(qf1, kf1, sv);
      s[ct] = sv;
    }
    const bool diag = (t0 + 63 > q0);
#pragma unroll
    for (int ct = 0; ct < 4; ++ct)
#pragma unroll
      for (int e = 0; e < 4; ++e) {
        float v = s[ct][e] * 0.125f;
        if (diag) {
          int qg = q0 + l4 * 4 + e;
          int tg = t0 + ct * 16 + l15;
          if (tg > qg) v = -1e30f;
        }
        s[ct][e] = v;
      }
#pragma unroll
    for (int e = 0; e < 4; ++e) {
      float mt = fmaxf(fmaxf(s[0][e], s[1][e]), fmaxf(s[2][e], s[3][e]));
      mt = fmaxf(mt, __shfl_xor(mt, 1));
      mt = fmaxf(mt, __shfl_xor(mt, 2));
      mt = fmaxf(mt, __shfl_xor(mt, 4));
      mt = fmaxf(mt, __shfl_xor(mt, 8));
      float mn = fmaxf(m_r[e], mt);
      float alpha = __expf(m_r[e] - mn);
      m_r[e] = mn;
      l_r[e] *= alpha;
      o[0][e] *= alpha; o[1][e] *= alpha; o[2][e] *= alpha; o[3][e] *= alpha;
      float rs = 0.f;
#pragma unroll
      for (int ct = 0; ct < 4; ++ct) {
        float p = __expf(s[ct][e] - mn);
        s[ct][e] = p;
        rs += p;
      }
      rs += __shfl_xor(rs, 1); rs += __shfl_xor(rs, 2);
      rs += __shfl_xor(rs, 4); rs += __shfl_xor(rs, 8);
      l_r[e] += rs;
    }
    __syncthreads();  // protect P from previous iteration's readers
#pragma unroll
    for (int ct = 0; ct < 4; ++ct)
#pragma unroll
      for (int e = 0; e < 4; ++e) {
        int r = l4 * 4 + e;
        int t = ct * 16 + l15;
        int slot = (t >> 3) ^ (r & 7);
        P[r * 64 + slot * 8 + (t & 7)] = f2bf(s[ct][e]);
      }
    __syncthreads();
#pragma unroll
    for (int kk = 0; kk < 2; ++kk) {
      int r = l15;
      int slotL = kk * 4 + l4;
      bf16x8 pf = *(const bf16x8*)&P[r * 64 + ((slotL ^ (r & 7)) * 8)];
#pragma unroll
      for (int cd = 0; cd < 4; ++cd) {
        const u16* vp = VT + (size_t)(g * 64 + cd * 16 + l15) * 4096 + b * 2048 + t0 + kk * 32 + l4 * 8;
        bf16x8 vf = *(const bf16x8*)vp;
        o[cd] = MFMA16(pf, vf, o[cd]);
      }
    }
  }
#pragma unroll
  for (int cd = 0; cd < 4; ++cd)
#pragma unroll
    for (int e = 0; e < 4; ++e) {
      int r = l4 * 4 + e;
      int d = cd * 16 + l15;
      float ov = o[cd][e] / l_r[e];
      AO[(size_t)(b * 2048 + q0 + r) * 2048 + h * 64 + d] = f2bf(ov);
    }
}

// ---------------- launcher ----------------
extern "C" void kernel_launch(void* const* d_in, const int* in_sizes, int n_in,
                              void* d_out, int out_size, void* d_ws, size_t ws_size,
                              hipStream_t stream) {
  const float* X  = (const float*)d_in[0];
  const float* Wq = (const float*)d_in[1];
  const float* Wk = (const float*)d_in[2];
  const float* Wv = (const float*)d_in[3];
  const float* Wo = (const float*)d_in[4];
  float* out = (float*)d_out;

  u16* ws  = (u16*)d_ws;
  u16* Xb  = ws;                 // 8,388,608 elems  [4096][2048]
  u16* WqT = Xb  + 8388608;      // 4,194,304        [2048][2048]
  u16* WkT = WqT + 4194304;      // 1,048,576        [512][2048]
  u16* WvT = WkT + 1048576;      // 1,048,576        [512][2048]
  u16* WoT = WvT + 1048576;      // 4,194,304        [2048][2048]
  u16* Qb  = WoT + 4194304;      // 8,388,608        [4096][2048]
  u16* Kbf = Qb  + 8388608;      // 2,097,152        [4096][512]
  u16* VTb = Kbf + 2097152;      // 2,097,152        [512][4096]
  u16* AOb = Xb;                 // alias X after projections are done

  cvt_x<<<8192, 256, 0, stream>>>(X, Xb, 2097152);
  dim3 tb(32, 32);
  transpose_cvt<<<dim3(64, 64), tb, 0, stream>>>(Wq, WqT, 2048, 2048);
  transpose_cvt<<<dim3(16, 64), tb, 0, stream>>>(Wk, WkT, 2048, 512);
  transpose_cvt<<<dim3(16, 64), tb, 0, stream>>>(Wv, WvT, 2048, 512);
  transpose_cvt<<<dim3(64, 64), tb, 0, stream>>>(Wo, WoT, 2048, 2048);

  gemm_bt<0><<<dim3(16, 32), 256, 0, stream>>>(Xb, WqT, Qb,  4096, 2048, 2048);
  gemm_bt<0><<<dim3(4, 32),  256, 0, stream>>>(Xb, WkT, Kbf, 4096, 512,  2048);
  gemm_bt<1><<<dim3(4, 32),  256, 0, stream>>>(Xb, WvT, VTb, 4096, 512,  2048);

  attn_fwd<<<dim3(128, 32, 2), 64, 0, stream>>>(Qb, Kbf, VTb, AOb);

  gemm_bt<2><<<dim3(16, 32), 256, 0, stream>>>(AOb, WoT, out, 4096, 2048, 2048);
}

// Round 2
// 420.229 us; speedup vs baseline: 1.2965x; 1.2965x over previous
//
#include <hip/hip_runtime.h>
#include <hip/hip_bf16.h>

typedef unsigned short u16;
typedef __bf16 bf16x8 __attribute__((ext_vector_type(8)));
typedef float f32x4 __attribute__((ext_vector_type(4)));
typedef unsigned short u16x4 __attribute__((ext_vector_type(4)));

#define MFMA16(a, b, c) __builtin_amdgcn_mfma_f32_16x16x32_bf16(a, b, c, 0, 0, 0)

__device__ __forceinline__ u16 f2bf(float f) {
  union { float f; unsigned u; } v; v.f = f;
  unsigned r = v.u + 0x7FFFu + ((v.u >> 16) & 1u);
  return (u16)(r >> 16);
}

__device__ __forceinline__ void gload16(const u16* g, u16* l) {
  __builtin_amdgcn_global_load_lds(
      (const __attribute__((address_space(1))) unsigned int*)g,
      (__attribute__((address_space(3))) unsigned int*)l, 16, 0, 0);
}

// ---------------- elementwise f32 -> bf16 ----------------
__global__ void cvt_x(const float* __restrict__ X, u16* __restrict__ Xb, int n4) {
  int i = blockIdx.x * blockDim.x + threadIdx.x;
  if (i < n4) {
    float4 v = ((const float4*)X)[i];
    u16x4 o = { f2bf(v.x), f2bf(v.y), f2bf(v.z), f2bf(v.w) };
    ((u16x4*)Xb)[i] = o;
  }
}

// ---------------- tiled transpose + convert: W[K][N] f32 -> WT[N][K] bf16 ----------------
__global__ void transpose_cvt(const float* __restrict__ W, u16* __restrict__ WT, int K, int N) {
  __shared__ float t[32][33];
  int n0 = blockIdx.x * 32, k0 = blockIdx.y * 32;
  int tx = threadIdx.x, ty = threadIdx.y;
  t[ty][tx] = W[(size_t)(k0 + ty) * N + n0 + tx];
  __syncthreads();
  WT[(size_t)(n0 + ty) * K + k0 + tx] = f2bf(t[tx][ty]);
}

// ---------------- GEMM: C[M][N] = A[M][K] @ BT[N][K]^T (bf16 in, f32 acc) ----------------
// STORE: 0 = bf16 row-major [M][N], 1 = bf16 transposed [N][M], 2 = f32 row-major [M][N]
template <int STORE>
__global__ __launch_bounds__(256) void gemm_bt(const u16* __restrict__ A,
                                               const u16* __restrict__ BT,
                                               void* __restrict__ Cv,
                                               int M, int N, int K) {
  __shared__ u16 lA[128 * 32];
  __shared__ u16 lB[128 * 32];
  const int tid = threadIdx.x;
  const int lane = tid & 63;
  const int wave = tid >> 6;
  const int wm = (wave >> 1) * 64, wn = (wave & 1) * 64;
  const int bm = blockIdx.y * 128, bn = blockIdx.x * 128;
  const int l15 = lane & 15, l4 = lane >> 4;

  f32x4 acc[4][4] = {};

  for (int k0 = 0; k0 < K; k0 += 32) {
    __syncthreads();
#pragma unroll
    for (int it = 0; it < 2; ++it) {
      int s = it * 256 + tid;
      int row = s >> 2, pkb = s & 3;
      int kb = pkb ^ ((row >> 1) & 3);  // pre-swizzled global source (both-sides rule)
      gload16(A + (size_t)(bm + row) * K + k0 + kb * 8, &lA[s * 8]);
      gload16(BT + (size_t)(bn + row) * K + k0 + kb * 8, &lB[s * 8]);
    }
    __syncthreads();
    bf16x8 af[4], bf[4];
#pragma unroll
    for (int i = 0; i < 4; ++i) {
      int r = wm + i * 16 + l15;
      int pk = l4 ^ ((r >> 1) & 3);
      af[i] = *(const bf16x8*)&lA[r * 32 + pk * 8];
      int n = wn + i * 16 + l15;
      int pkn = l4 ^ ((n >> 1) & 3);
      bf[i] = *(const bf16x8*)&lB[n * 32 + pkn * 8];
    }
#pragma unroll
    for (int i = 0; i < 4; ++i)
#pragma unroll
      for (int j = 0; j < 4; ++j)
        acc[i][j] = MFMA16(af[i], bf[j], acc[i][j]);
  }

#pragma unroll
  for (int i = 0; i < 4; ++i) {
    int row = bm + wm + i * 16 + l4 * 4;
#pragma unroll
    for (int j = 0; j < 4; ++j) {
      int col = bn + wn + j * 16 + l15;
#pragma unroll
      for (int e = 0; e < 4; ++e) {
        float v = acc[i][j][e];
        if (STORE == 0)      ((u16*)Cv)[(size_t)(row + e) * N + col] = f2bf(v);
        else if (STORE == 1) ((u16*)Cv)[(size_t)col * M + (row + e)] = f2bf(v);
        else                 ((float*)Cv)[(size_t)(row + e) * N + col] = v;
      }
    }
  }
}

// ---------------- causal flash attention, 8-wave blocks ----------------
// Q: [B*S][2048] bf16 (col = h*64+d), K: [B*S][512] bf16 (col = g*64+d),
// VT: [512][B*S] bf16 (row = g*64+d), AO: [B*S][2048] bf16
// grid (S/32, G, B), block = 512 (8 waves = 4 heads sharing group g x 2 q-halves).
// head h = a*8 + g attends group g (reference reshape mapping).
__global__ __launch_bounds__(512) void attn_fwd(const u16* __restrict__ Q,
                                                const u16* __restrict__ Kb,
                                                const u16* __restrict__ VT,
                                                u16* __restrict__ AO) {
  const int qb = blockIdx.x, g = blockIdx.y, b = blockIdx.z;
  const int tid = threadIdx.x;
  const int lane = tid & 63;
  const int wave = tid >> 6;
  const int a = wave >> 1;                  // head sub-index, h = a*8+g
  const int h = a * 8 + g;
  const int qw0 = qb * 32 + (wave & 1) * 16;  // this wave's first q row
  const int l15 = lane & 15, l4 = lane >> 4;

  __shared__ u16 Klds[64 * 64];   // [t][d], chunk-XOR swizzled
  __shared__ u16 Vlds[64 * 64];   // [d][t], chunk-XOR swizzled
  __shared__ u16 Plds[8][16 * 64];

  const u16* qp = Q + (size_t)(b * 2048 + qw0 + l15) * 2048 + h * 64 + l4 * 8;
  bf16x8 qf0 = *(const bf16x8*)qp;
  bf16x8 qf1 = *(const bf16x8*)(qp + 32);

  float m_r[4], l_r[4];
  f32x4 o[4] = {};
#pragma unroll
  for (int j = 0; j < 4; ++j) { m_r[j] = -1e30f; l_r[j] = 0.f; }

  // staging coords: slot = tid, row = tid>>3, chunk c = tid&7, src chunk swizzled
  const int srow = tid >> 3, sc = (tid & 7) ^ (srow & 7);

  const int tmax = qb * 32 + 31;  // last q row in block
  for (int t0 = 0; t0 <= tmax; t0 += 64) {
    __syncthreads();  // previous tile's LDS reads complete
    gload16(Kb + (size_t)(b * 2048 + t0 + srow) * 512 + g * 64 + sc * 8, &Klds[tid * 8]);
    gload16(VT + (size_t)(g * 64 + srow) * 4096 + b * 2048 + t0 + sc * 8, &Vlds[tid * 8]);
    __syncthreads();  // staging visible (vmcnt+lgkm drained by barrier semantics)

    if (t0 <= qw0 + 15) {  // wave has at least one unmasked row in this tile
      f32x4 s[4];
#pragma unroll
      for (int ct = 0; ct < 4; ++ct) {
        int t = ct * 16 + l15;
        bf16x8 kf0 = *(const bf16x8*)&Klds[(t * 8 + (l4 ^ (t & 7))) * 8];
        bf16x8 kf1 = *(const bf16x8*)&Klds[(t * 8 + ((l4 + 4) ^ (t & 7))) * 8];
        f32x4 sv = {0.f, 0.f, 0.f, 0.f};
        sv = MFMA16(qf0, kf0, sv);
        sv = MFMA16(qf1, kf1, sv);
        s[ct] = sv;
      }
      const bool diag = (t0 + 63 > qw0);
#pragma unroll
      for (int ct = 0; ct < 4; ++ct)
#pragma unroll
        for (int e = 0; e < 4; ++e) {
          float v = s[ct][e] * 0.125f;
          if (diag) {
            int qg = qw0 + l4 * 4 + e;
            int tg = t0 + ct * 16 + l15;
            if (tg > qg) v = -1e30f;
          }
          s[ct][e] = v;
        }
#pragma unroll
      for (int e = 0; e < 4; ++e) {
        float mt = fmaxf(fmaxf(s[0][e], s[1][e]), fmaxf(s[2][e], s[3][e]));
        mt = fmaxf(mt, __shfl_xor(mt, 1));
        mt = fmaxf(mt, __shfl_xor(mt, 2));
        mt = fmaxf(mt, __shfl_xor(mt, 4));
        mt = fmaxf(mt, __shfl_xor(mt, 8));
        float mn = fmaxf(m_r[e], mt);
        float alpha = __expf(m_r[e] - mn);
        m_r[e] = mn;
        l_r[e] *= alpha;
        o[0][e] *= alpha; o[1][e] *= alpha; o[2][e] *= alpha; o[3][e] *= alpha;
        float rs = 0.f;
#pragma unroll
        for (int ct = 0; ct < 4; ++ct) {
          float p = __expf(s[ct][e] - mn);
          s[ct][e] = p;
          rs += p;
        }
        rs += __shfl_xor(rs, 1); rs += __shfl_xor(rs, 2);
        rs += __shfl_xor(rs, 4); rs += __shfl_xor(rs, 8);
        l_r[e] += rs;
      }
      // P transpose through per-wave LDS (same-wave DS ordering, no barrier)
      u16* P = Plds[wave];
#pragma unroll
      for (int ct = 0; ct < 4; ++ct)
#pragma unroll
        for (int e = 0; e < 4; ++e) {
          int r = l4 * 4 + e;
          int t = ct * 16 + l15;
          int slot = (t >> 3) ^ (r & 7);
          P[r * 64 + slot * 8 + (t & 7)] = f2bf(s[ct][e]);
        }
#pragma unroll
      for (int kk = 0; kk < 2; ++kk) {
        int r = l15;
        int slotL = kk * 4 + l4;
        bf16x8 pf = *(const bf16x8*)&P[r * 64 + ((slotL ^ (r & 7)) * 8)];
#pragma unroll
        for (int cd = 0; cd < 4; ++cd) {
          int d = cd * 16 + l15;
          bf16x8 vf = *(const bf16x8*)&Vlds[(d * 8 + ((kk * 4 + l4) ^ (d & 7))) * 8];
          o[cd] = MFMA16(pf, vf, o[cd]);
        }
      }
    }
  }

#pragma unroll
  for (int cd = 0; cd < 4; ++cd)
#pragma unroll
    for (int e = 0; e < 4; ++e) {
      int r = l4 * 4 + e;
      int d = cd * 16 + l15;
      float ov = o[cd][e] / l_r[e];
      AO[(size_t)(b * 2048 + qw0 + r) * 2048 + h * 64 + d] = f2bf(ov);
    }
}

// ---------------- launcher ----------------
extern "C" void kernel_launch(void* const* d_in, const int* in_sizes, int n_in,
                              void* d_out, int out_size, void* d_ws, size_t ws_size,
                              hipStream_t stream) {
  const float* X  = (const float*)d_in[0];
  const float* Wq = (const float*)d_in[1];
  const float* Wk = (const float*)d_in[2];
  const float* Wv = (const float*)d_in[3];
  const float* Wo = (const float*)d_in[4];
  float* out = (float*)d_out;

  u16* ws  = (u16*)d_ws;
  u16* Xb  = ws;                 // 8,388,608 elems  [4096][2048]
  u16* WqT = Xb  + 8388608;      // 4,194,304        [2048][2048]
  u16* WkT = WqT + 4194304;      // 1,048,576        [512][2048]
  u16* WvT = WkT + 1048576;      // 1,048,576        [512][2048]
  u16* WoT = WvT + 1048576;      // 4,194,304        [2048][2048]
  u16* Qb  = WoT + 4194304;      // 8,388,608        [4096][2048]
  u16* Kbf = Qb  + 8388608;      // 2,097,152        [4096][512]
  u16* VTb = Kbf + 2097152;      // 2,097,152        [512][4096]
  u16* AOb = Xb;                 // alias X after projections are done

  cvt_x<<<8192, 256, 0, stream>>>(X, Xb, 2097152);
  dim3 tb(32, 32);
  transpose_cvt<<<dim3(64, 64), tb, 0, stream>>>(Wq, WqT, 2048, 2048);
  transpose_cvt<<<dim3(16, 64), tb, 0, stream>>>(Wk, WkT, 2048, 512);
  transpose_cvt<<<dim3(16, 64), tb, 0, stream>>>(Wv, WvT, 2048, 512);
  transpose_cvt<<<dim3(64, 64), tb, 0, stream>>>(Wo, WoT, 2048, 2048);

  gemm_bt<0><<<dim3(16, 32), 256, 0, stream>>>(Xb, WqT, Qb,  4096, 2048, 2048);
  gemm_bt<0><<<dim3(4, 32),  256, 0, stream>>>(Xb, WkT, Kbf, 4096, 512,  2048);
  gemm_bt<1><<<dim3(4, 32),  256, 0, stream>>>(Xb, WvT, VTb, 4096, 512,  2048);

  attn_fwd<<<dim3(64, 8, 2), 512, 0, stream>>>(Qb, Kbf, VTb, AOb);

  gemm_bt<2><<<dim3(16, 32), 256, 0, stream>>>(AOb, WoT, out, 4096, 2048, 2048);
}

// Round 3
// 339.103 us; speedup vs baseline: 1.6067x; 1.2392x over previous
//
#include <hip/hip_runtime.h>
#include <hip/hip_bf16.h>

typedef unsigned short u16;
typedef __bf16 bf16x8 __attribute__((ext_vector_type(8)));
typedef float f32x4 __attribute__((ext_vector_type(4)));
typedef unsigned short u16x4 __attribute__((ext_vector_type(4)));

#define MFMA16(a, b, c) __builtin_amdgcn_mfma_f32_16x16x32_bf16(a, b, c, 0, 0, 0)

__device__ __forceinline__ u16 f2bf(float f) {
  union { float f; unsigned u; } v; v.f = f;
  unsigned r = v.u + 0x7FFFu + ((v.u >> 16) & 1u);
  return (u16)(r >> 16);
}

__device__ __forceinline__ void gload16(const u16* g, u16* l) {
  __builtin_amdgcn_global_load_lds(
      (const __attribute__((address_space(1))) unsigned int*)g,
      (__attribute__((address_space(3))) unsigned int*)l, 16, 0, 0);
}

// ---------------- elementwise f32 -> bf16 ----------------
__global__ void cvt_x(const float* __restrict__ X, u16* __restrict__ Xb, int n4) {
  int i = blockIdx.x * blockDim.x + threadIdx.x;
  if (i < n4) {
    float4 v = ((const float4*)X)[i];
    u16x4 o = { f2bf(v.x), f2bf(v.y), f2bf(v.z), f2bf(v.w) };
    ((u16x4*)Xb)[i] = o;
  }
}

// ---------------- tiled transpose + convert: W[K][N] f32 -> WT[N][K] bf16 ----------------
__global__ void transpose_cvt(const float* __restrict__ W, u16* __restrict__ WT, int K, int N) {
  __shared__ float t[32][33];
  int n0 = blockIdx.x * 32, k0 = blockIdx.y * 32;
  int tx = threadIdx.x, ty = threadIdx.y;
  t[ty][tx] = W[(size_t)(k0 + ty) * N + n0 + tx];
  __syncthreads();
  WT[(size_t)(n0 + ty) * K + k0 + tx] = f2bf(t[tx][ty]);
}

// ---------------- GEMM: C[M][N] = A[M][K] @ BT[N][K]^T (bf16 in, f32 acc) ----------------
// STORE: 0 = bf16 row-major [M][N], 1 = bf16 transposed [N][M], 2 = f32 row-major [M][N]
template <int STORE>
__global__ __launch_bounds__(256) void gemm_bt(const u16* __restrict__ A,
                                               const u16* __restrict__ BT,
                                               void* __restrict__ Cv,
                                               int M, int N, int K) {
  __shared__ u16 lA[128 * 32];
  __shared__ u16 lB[128 * 32];
  const int tid = threadIdx.x;
  const int lane = tid & 63;
  const int wave = tid >> 6;
  const int wm = (wave >> 1) * 64, wn = (wave & 1) * 64;
  const int bm = blockIdx.y * 128, bn = blockIdx.x * 128;
  const int l15 = lane & 15, l4 = lane >> 4;

  f32x4 acc[4][4] = {};

  for (int k0 = 0; k0 < K; k0 += 32) {
    __syncthreads();
#pragma unroll
    for (int it = 0; it < 2; ++it) {
      int s = it * 256 + tid;
      int row = s >> 2, pkb = s & 3;
      int kb = pkb ^ ((row >> 1) & 3);  // pre-swizzled global source (both-sides rule)
      gload16(A + (size_t)(bm + row) * K + k0 + kb * 8, &lA[s * 8]);
      gload16(BT + (size_t)(bn + row) * K + k0 + kb * 8, &lB[s * 8]);
    }
    __syncthreads();
    bf16x8 af[4], bf[4];
#pragma unroll
    for (int i = 0; i < 4; ++i) {
      int r = wm + i * 16 + l15;
      int pk = l4 ^ ((r >> 1) & 3);
      af[i] = *(const bf16x8*)&lA[r * 32 + pk * 8];
      int n = wn + i * 16 + l15;
      int pkn = l4 ^ ((n >> 1) & 3);
      bf[i] = *(const bf16x8*)&lB[n * 32 + pkn * 8];
    }
#pragma unroll
    for (int i = 0; i < 4; ++i)
#pragma unroll
      for (int j = 0; j < 4; ++j)
        acc[i][j] = MFMA16(af[i], bf[j], acc[i][j]);
  }

#pragma unroll
  for (int i = 0; i < 4; ++i) {
    int row = bm + wm + i * 16 + l4 * 4;
#pragma unroll
    for (int j = 0; j < 4; ++j) {
      int col = bn + wn + j * 16 + l15;
#pragma unroll
      for (int e = 0; e < 4; ++e) {
        float v = acc[i][j][e];
        if (STORE == 0)      ((u16*)Cv)[(size_t)(row + e) * N + col] = f2bf(v);
        else if (STORE == 1) ((u16*)Cv)[(size_t)col * M + (row + e)] = f2bf(v);
        else                 ((float*)Cv)[(size_t)(row + e) * N + col] = v;
      }
    }
  }
}

// ---------------- causal flash attention, 8-wave blocks, dbuf prefetch, balanced pairs ----
// Q: [B*S][2048] bf16 (col = h*64+d), K: [B*S][512] bf16 (col = g*64+d),
// VT: [512][B*S] bf16 (row = g*64+d), AO: [B*S][2048] bf16
// grid (32, G, B), block = 512 (8 waves = 4 heads x 2 q-subtiles of 16 rows).
// Block handles q-tiles {pair, 63-pair} sequentially -> uniform ~33 tiles/block.
// head h = a*8 + g attends group g (reference reshape mapping).
__global__ __launch_bounds__(512) void attn_fwd(const u16* __restrict__ Q,
                                                const u16* __restrict__ Kb,
                                                const u16* __restrict__ VT,
                                                u16* __restrict__ AO) {
  const int pair = blockIdx.x, g = blockIdx.y, b = blockIdx.z;
  const int tid = threadIdx.x;
  const int lane = tid & 63;
  const int wave = tid >> 6;
  const int a = wave >> 1;                  // head sub-index, h = a*8+g
  const int h = a * 8 + g;
  const int l15 = lane & 15, l4 = lane >> 4;

  __shared__ u16 Klds[2][64 * 64];   // [t][d], chunk-XOR swizzled
  __shared__ u16 Vlds[2][64 * 64];   // [d][t], chunk-XOR swizzled
  __shared__ u16 Plds[8][16 * 64];

  // staging coords: slot = tid, row = tid>>3, chunk c = tid&7, src chunk swizzled
  const int srow = tid >> 3, sc = (tid & 7) ^ (srow & 7);

  int cur = 0;
#pragma unroll 1
  for (int pass = 0; pass < 2; ++pass) {
    const int qt = (pass == 0) ? pair : 63 - pair;
    const int qw0 = qt * 32 + (wave & 1) * 16;  // this wave's first q row
    const int nt = qt / 2 + 1;                  // K/V tiles for this q-tile

    const u16* qp = Q + (size_t)(b * 2048 + qw0 + l15) * 2048 + h * 64 + l4 * 8;
    bf16x8 qf0 = *(const bf16x8*)qp;
    bf16x8 qf1 = *(const bf16x8*)(qp + 32);

    float m_r[4], l_r[4];
    f32x4 o[4] = {};
#pragma unroll
    for (int j = 0; j < 4; ++j) { m_r[j] = -1e30f; l_r[j] = 0.f; }

    // prologue: stage tile 0
    {
      gload16(Kb + (size_t)(b * 2048 + 0 + srow) * 512 + g * 64 + sc * 8, &Klds[cur][tid * 8]);
      gload16(VT + (size_t)(g * 64 + srow) * 4096 + b * 2048 + 0 + sc * 8, &Vlds[cur][tid * 8]);
      asm volatile("s_waitcnt vmcnt(0)" ::: "memory");
      __builtin_amdgcn_s_barrier();
    }

#pragma unroll 1
    for (int ti = 0; ti < nt; ++ti) {
      const int t0 = ti * 64;
      // issue prefetch of next tile into the other buffer
      if (ti + 1 < nt) {
        const int tn = t0 + 64;
        gload16(Kb + (size_t)(b * 2048 + tn + srow) * 512 + g * 64 + sc * 8, &Klds[cur ^ 1][tid * 8]);
        gload16(VT + (size_t)(g * 64 + srow) * 4096 + b * 2048 + tn + sc * 8, &Vlds[cur ^ 1][tid * 8]);
      }

      if (t0 <= qw0 + 15) {  // wave has at least one unmasked row in this tile
        const u16* Kc = Klds[cur];
        const u16* Vc = Vlds[cur];
        f32x4 s[4];
        __builtin_amdgcn_s_setprio(1);
#pragma unroll
        for (int ct = 0; ct < 4; ++ct) {
          int t = ct * 16 + l15;
          bf16x8 kf0 = *(const bf16x8*)&Kc[(t * 8 + (l4 ^ (t & 7))) * 8];
          bf16x8 kf1 = *(const bf16x8*)&Kc[(t * 8 + ((l4 + 4) ^ (t & 7))) * 8];
          f32x4 sv = {0.f, 0.f, 0.f, 0.f};
          sv = MFMA16(qf0, kf0, sv);
          sv = MFMA16(qf1, kf1, sv);
          s[ct] = sv;
        }
        __builtin_amdgcn_s_setprio(0);
        const bool diag = (t0 + 63 > qw0);
#pragma unroll
        for (int ct = 0; ct < 4; ++ct)
#pragma unroll
          for (int e = 0; e < 4; ++e) {
            float v = s[ct][e] * 0.125f;
            if (diag) {
              int qg = qw0 + l4 * 4 + e;
              int tg = t0 + ct * 16 + l15;
              if (tg > qg) v = -1e30f;
            }
            s[ct][e] = v;
          }
#pragma unroll
        for (int e = 0; e < 4; ++e) {
          float mt = fmaxf(fmaxf(s[0][e], s[1][e]), fmaxf(s[2][e], s[3][e]));
          mt = fmaxf(mt, __shfl_xor(mt, 1));
          mt = fmaxf(mt, __shfl_xor(mt, 2));
          mt = fmaxf(mt, __shfl_xor(mt, 4));
          mt = fmaxf(mt, __shfl_xor(mt, 8));
          float mn = fmaxf(m_r[e], mt);
          float alpha = __expf(m_r[e] - mn);
          m_r[e] = mn;
          l_r[e] *= alpha;
          o[0][e] *= alpha; o[1][e] *= alpha; o[2][e] *= alpha; o[3][e] *= alpha;
          float rs = 0.f;
#pragma unroll
          for (int ct = 0; ct < 4; ++ct) {
            float p = __expf(s[ct][e] - mn);
            s[ct][e] = p;
            rs += p;
          }
          rs += __shfl_xor(rs, 1); rs += __shfl_xor(rs, 2);
          rs += __shfl_xor(rs, 4); rs += __shfl_xor(rs, 8);
          l_r[e] += rs;
        }
        // P transpose through per-wave LDS (same-wave DS ordering, no barrier)
        u16* P = Plds[wave];
#pragma unroll
        for (int ct = 0; ct < 4; ++ct)
#pragma unroll
          for (int e = 0; e < 4; ++e) {
            int r = l4 * 4 + e;
            int t = ct * 16 + l15;
            int slot = (t >> 3) ^ (r & 7);
            P[r * 64 + slot * 8 + (t & 7)] = f2bf(s[ct][e]);
          }
        __builtin_amdgcn_s_setprio(1);
#pragma unroll
        for (int kk = 0; kk < 2; ++kk) {
          int r = l15;
          int slotL = kk * 4 + l4;
          bf16x8 pf = *(const bf16x8*)&P[r * 64 + ((slotL ^ (r & 7)) * 8)];
#pragma unroll
          for (int cd = 0; cd < 4; ++cd) {
            int d = cd * 16 + l15;
            bf16x8 vf = *(const bf16x8*)&Vc[(d * 8 + ((kk * 4 + l4) ^ (d & 7))) * 8];
            o[cd] = MFMA16(pf, vf, o[cd]);
          }
        }
        __builtin_amdgcn_s_setprio(0);
      }

      // single drain+barrier per tile: prefetch loads land, all reads of cur done
      asm volatile("s_waitcnt vmcnt(0)" ::: "memory");
      __builtin_amdgcn_s_barrier();
      cur ^= 1;
    }

#pragma unroll
    for (int cd = 0; cd < 4; ++cd)
#pragma unroll
      for (int e = 0; e < 4; ++e) {
        int r = l4 * 4 + e;
        int d = cd * 16 + l15;
        float ov = o[cd][e] / l_r[e];
        AO[(size_t)(b * 2048 + qw0 + r) * 2048 + h * 64 + d] = f2bf(ov);
      }
  }
}

// ---------------- launcher ----------------
extern "C" void kernel_launch(void* const* d_in, const int* in_sizes, int n_in,
                              void* d_out, int out_size, void* d_ws, size_t ws_size,
                              hipStream_t stream) {
  const float* X  = (const float*)d_in[0];
  const float* Wq = (const float*)d_in[1];
  const float* Wk = (const float*)d_in[2];
  const float* Wv = (const float*)d_in[3];
  const float* Wo = (const float*)d_in[4];
  float* out = (float*)d_out;

  u16* ws  = (u16*)d_ws;
  u16* Xb  = ws;                 // 8,388,608 elems  [4096][2048]
  u16* WqT = Xb  + 8388608;      // 4,194,304        [2048][2048]
  u16* WkT = WqT + 4194304;      // 1,048,576        [512][2048]
  u16* WvT = WkT + 1048576;      // 1,048,576        [512][2048]
  u16* WoT = WvT + 1048576;      // 4,194,304        [2048][2048]
  u16* Qb  = WoT + 4194304;      // 8,388,608        [4096][2048]
  u16* Kbf = Qb  + 8388608;      // 2,097,152        [4096][512]
  u16* VTb = Kbf + 2097152;      // 2,097,152        [512][4096]
  u16* AOb = Xb;                 // alias X after projections are done

  cvt_x<<<8192, 256, 0, stream>>>(X, Xb, 2097152);
  dim3 tb(32, 32);
  transpose_cvt<<<dim3(64, 64), tb, 0, stream>>>(Wq, WqT, 2048, 2048);
  transpose_cvt<<<dim3(16, 64), tb, 0, stream>>>(Wk, WkT, 2048, 512);
  transpose_cvt<<<dim3(16, 64), tb, 0, stream>>>(Wv, WvT, 2048, 512);
  transpose_cvt<<<dim3(64, 64), tb, 0, stream>>>(Wo, WoT, 2048, 2048);

  gemm_bt<0><<<dim3(16, 32), 256, 0, stream>>>(Xb, WqT, Qb,  4096, 2048, 2048);
  gemm_bt<0><<<dim3(4, 32),  256, 0, stream>>>(Xb, WkT, Kbf, 4096, 512,  2048);
  gemm_bt<1><<<dim3(4, 32),  256, 0, stream>>>(Xb, WvT, VTb, 4096, 512,  2048);

  attn_fwd<<<dim3(32, 8, 2), 512, 0, stream>>>(Qb, Kbf, VTb, AOb);

  gemm_bt<2><<<dim3(16, 32), 256, 0, stream>>>(AOb, WoT, out, 4096, 2048, 2048);
}

// Round 5
// 230.371 us; speedup vs baseline: 2.3650x; 1.4720x over previous
//
#include <hip/hip_runtime.h>
#include <hip/hip_bf16.h>

typedef unsigned short u16;
typedef __bf16 bf16x8 __attribute__((ext_vector_type(8)));
typedef float f32x4 __attribute__((ext_vector_type(4)));
typedef unsigned short u16x4 __attribute__((ext_vector_type(4)));

#define MFMA16(a, b, c) __builtin_amdgcn_mfma_f32_16x16x32_bf16(a, b, c, 0, 0, 0)

__device__ __forceinline__ u16 f2bf(float f) {
  union { float f; unsigned u; } v; v.f = f;
  unsigned r = v.u + 0x7FFFu + ((v.u >> 16) & 1u);
  return (u16)(r >> 16);
}

__device__ __forceinline__ u16 f2bf_native(float f) {
  __hip_bfloat16 hb = __float2bfloat16(f);
  u16 out;
  __builtin_memcpy(&out, &hb, 2);
  return out;
}

__device__ __forceinline__ void gload16(const u16* g, u16* l) {
  __builtin_amdgcn_global_load_lds(
      (const __attribute__((address_space(1))) unsigned int*)g,
      (__attribute__((address_space(3))) unsigned int*)l, 16, 0, 0);
}

// ---------------- elementwise f32 -> bf16 ----------------
__global__ void cvt_x(const float* __restrict__ X, u16* __restrict__ Xb, int n4) {
  int i = blockIdx.x * blockDim.x + threadIdx.x;
  if (i < n4) {
    float4 v = ((const float4*)X)[i];
    u16x4 o = { f2bf(v.x), f2bf(v.y), f2bf(v.z), f2bf(v.w) };
    ((u16x4*)Xb)[i] = o;
  }
}

// ---------------- tiled transpose + convert: W[K][N] f32 -> WT[N][K] bf16 ----------------
__global__ void transpose_cvt(const float* __restrict__ W, u16* __restrict__ WT, int K, int N) {
  __shared__ float t[32][33];
  int n0 = blockIdx.x * 32, k0 = blockIdx.y * 32;
  int tx = threadIdx.x, ty = threadIdx.y;
  t[ty][tx] = W[(size_t)(k0 + ty) * N + n0 + tx];
  __syncthreads();
  WT[(size_t)(n0 + ty) * K + k0 + tx] = f2bf(t[tx][ty]);
}

// ---------------- GEMM: C[M][N] = A[M][K] @ BT[N][K]^T (bf16 in, f32 acc) ----------------
// STORE: 2 = f32 row-major [M][N]
// STORE: 4 = fused QKV store: cols [0,2048) -> Q bf16 scaled 0.125, [2048,2560) -> K bf16,
//            [2560,3072) -> V stored transposed [512][4096]. Cv = Qb base (fixed ws layout).
template <int STORE>
__global__ __launch_bounds__(256) void gemm_bt(const u16* __restrict__ A,
                                               const u16* __restrict__ BT,
                                               void* __restrict__ Cv,
                                               int M, int N, int K) {
  __shared__ u16 lA[128 * 32];
  __shared__ u16 lB[128 * 32];
  const int tid = threadIdx.x;
  const int lane = tid & 63;
  const int wave = tid >> 6;
  const int wm = (wave >> 1) * 64, wn = (wave & 1) * 64;
  const int bm = blockIdx.y * 128, bn = blockIdx.x * 128;
  const int l15 = lane & 15, l4 = lane >> 4;

  f32x4 acc[4][4] = {};

  for (int k0 = 0; k0 < K; k0 += 32) {
    __syncthreads();
#pragma unroll
    for (int it = 0; it < 2; ++it) {
      int s = it * 256 + tid;
      int row = s >> 2, pkb = s & 3;
      int kb = pkb ^ ((row >> 1) & 3);  // pre-swizzled global source (both-sides rule)
      gload16(A + (size_t)(bm + row) * K + k0 + kb * 8, &lA[s * 8]);
      gload16(BT + (size_t)(bn + row) * K + k0 + kb * 8, &lB[s * 8]);
    }
    __syncthreads();
    bf16x8 af[4], bf[4];
#pragma unroll
    for (int i = 0; i < 4; ++i) {
      int r = wm + i * 16 + l15;
      int pk = l4 ^ ((r >> 1) & 3);
      af[i] = *(const bf16x8*)&lA[r * 32 + pk * 8];
      int n = wn + i * 16 + l15;
      int pkn = l4 ^ ((n >> 1) & 3);
      bf[i] = *(const bf16x8*)&lB[n * 32 + pkn * 8];
    }
#pragma unroll
    for (int i = 0; i < 4; ++i)
#pragma unroll
      for (int j = 0; j < 4; ++j)
        acc[i][j] = MFMA16(af[i], bf[j], acc[i][j]);
  }

#pragma unroll
  for (int i = 0; i < 4; ++i) {
    int row = bm + wm + i * 16 + l4 * 4;
#pragma unroll
    for (int j = 0; j < 4; ++j) {
      int col = bn + wn + j * 16 + l15;
#pragma unroll
      for (int e = 0; e < 4; ++e) {
        float v = acc[i][j][e];
        if (STORE == 2) {
          ((float*)Cv)[(size_t)(row + e) * N + col] = v;
        } else {  // STORE == 4, fused QKV
          u16* Qb = (u16*)Cv;
          u16* Kb = Qb + 8388608;
          u16* Vt = Kb + 2097152;
          if (col < 2048)       Qb[(size_t)(row + e) * 2048 + col] = f2bf(v * 0.125f);
          else if (col < 2560)  Kb[(size_t)(row + e) * 512 + (col - 2048)] = f2bf(v);
          else                  Vt[(size_t)(col - 2560) * 4096 + (row + e)] = f2bf(v);
        }
      }
    }
  }
}

// ---------------- causal flash attention, 8-wave blocks, swapped-QK softmax ----
// Q: [B*S][2048] bf16 pre-scaled by 0.125 (col = h*64+d), K: [B*S][512] bf16,
// VT: [512][B*S] bf16 (row = g*64+d), AO: [B*S][2048] bf16
// grid (32, G, B), block = 512 (8 waves = 4 heads x 2 q-subtiles of 16 rows).
// Block handles q-tiles {pair, 63-pair} sequentially -> uniform ~33 tiles/block.
// head h = a*8 + g attends group g (reference reshape mapping).
// Swapped QK^T: S = mfma(K, Q) -> lane holds column q = lane&15, rows t = ct*16 + l4*4 + e.
__global__ __launch_bounds__(512) void attn_fwd(const u16* __restrict__ Q,
                                                const u16* __restrict__ Kb,
                                                const u16* __restrict__ VT,
                                                u16* __restrict__ AO) {
  const int pair = blockIdx.x, g = blockIdx.y, b = blockIdx.z;
  const int tid = threadIdx.x;
  const int lane = tid & 63;
  const int wave = tid >> 6;
  const int a = wave >> 1;                  // head sub-index, h = a*8+g
  const int h = a * 8 + g;
  const int l15 = lane & 15, l4 = lane >> 4;

  __shared__ u16 Klds[2][64 * 64];   // [t][d], chunk-XOR swizzled
  __shared__ u16 Vlds[2][64 * 64];   // [d][t], chunk-XOR swizzled
  __shared__ u16 Plds[8][16 * 64];   // per-wave P, [q][t], 16B-slot XOR swizzled

  // staging coords: slot = tid, row = tid>>3, chunk c = tid&7, src chunk swizzled
  const int srow = tid >> 3, sc = (tid & 7) ^ (srow & 7);

  int cur = 0;
#pragma unroll 1
  for (int pass = 0; pass < 2; ++pass) {
    const int qt = (pass == 0) ? pair : 63 - pair;
    const int qw0 = qt * 32 + (wave & 1) * 16;  // this wave's first q row
    const int nt = qt / 2 + 1;                  // K/V tiles for this q-tile

    const u16* qp = Q + (size_t)(b * 2048 + qw0 + l15) * 2048 + h * 64 + l4 * 8;
    bf16x8 qf0 = *(const bf16x8*)qp;
    bf16x8 qf1 = *(const bf16x8*)(qp + 32);

    float m_r = -1e30f, l_r = 0.f;
    f32x4 o[4] = {};

    // prologue: stage tile 0
    {
      gload16(Kb + (size_t)(b * 2048 + 0 + srow) * 512 + g * 64 + sc * 8, &Klds[cur][tid * 8]);
      gload16(VT + (size_t)(g * 64 + srow) * 4096 + b * 2048 + 0 + sc * 8, &Vlds[cur][tid * 8]);
      asm volatile("s_waitcnt vmcnt(0)" ::: "memory");
      __builtin_amdgcn_s_barrier();
    }

#pragma unroll 1
    for (int ti = 0; ti < nt; ++ti) {
      const int t0 = ti * 64;
      // issue prefetch of next tile into the other buffer
      if (ti + 1 < nt) {
        const int tn = t0 + 64;
        gload16(Kb + (size_t)(b * 2048 + tn + srow) * 512 + g * 64 + sc * 8, &Klds[cur ^ 1][tid * 8]);
        gload16(VT + (size_t)(g * 64 + srow) * 4096 + b * 2048 + tn + sc * 8, &Vlds[cur ^ 1][tid * 8]);
      }

      if (t0 <= qw0 + 15) {  // wave has at least one unmasked row in this tile
        const u16* Kc = Klds[cur];
        const u16* Vc = Vlds[cur];
        f32x4 s[4];
        __builtin_amdgcn_s_setprio(1);
#pragma unroll
        for (int ct = 0; ct < 4; ++ct) {
          int t = ct * 16 + l15;
          bf16x8 kf0 = *(const bf16x8*)&Kc[(t * 8 + (l4 ^ (t & 7))) * 8];
          bf16x8 kf1 = *(const bf16x8*)&Kc[(t * 8 + ((l4 + 4) ^ (t & 7))) * 8];
          f32x4 sv = {0.f, 0.f, 0.f, 0.f};
          sv = MFMA16(kf0, qf0, sv);   // swapped: S[t][q]
          sv = MFMA16(kf1, qf1, sv);
          s[ct] = sv;
        }
        __builtin_amdgcn_s_setprio(0);

        // causal mask (Q pre-scaled; no scale here). lane's q = qw0+l15, t = t0+ct*16+l4*4+e
        if (t0 + 63 > qw0) {
          const int qg = qw0 + l15;
#pragma unroll
          for (int ct = 0; ct < 4; ++ct)
#pragma unroll
            for (int e = 0; e < 4; ++e) {
              int tg = t0 + ct * 16 + l4 * 4 + e;
              if (tg > qg) s[ct][e] = -1e30f;
            }
        }

        // in-lane max over 16 values, then cross-l4 reduce (2 shfl)
        float m0 = fmaxf(fmaxf(s[0][0], s[0][1]), fmaxf(s[0][2], s[0][3]));
        float m1 = fmaxf(fmaxf(s[1][0], s[1][1]), fmaxf(s[1][2], s[1][3]));
        float m2 = fmaxf(fmaxf(s[2][0], s[2][1]), fmaxf(s[2][2], s[2][3]));
        float m3 = fmaxf(fmaxf(s[3][0], s[3][1]), fmaxf(s[3][2], s[3][3]));
        float mt = fmaxf(fmaxf(m0, m1), fmaxf(m2, m3));
        mt = fmaxf(mt, __shfl_xor(mt, 16));
        mt = fmaxf(mt, __shfl_xor(mt, 32));

        // defer-max (T13): skip rescale when max growth small
        if (!__all(mt <= m_r + 8.0f)) {
          float mn = fmaxf(m_r, mt);
          float alpha = __expf(m_r - mn);
          m_r = mn;
          l_r *= alpha;
#pragma unroll
          for (int e = 0; e < 4; ++e) {
            float ae = __shfl(alpha, l4 * 4 + e);  // alpha for q-row l4*4+e lives at lane l4*4+e
            o[0][e] *= ae; o[1][e] *= ae; o[2][e] *= ae; o[3][e] *= ae;
          }
        }

        // exp + sum + pack + P-write (4x ds_write_b64, 16B-slot swizzle)
        u16* P = Plds[wave];
        float rs = 0.f;
#pragma unroll
        for (int ct = 0; ct < 4; ++ct) {
          u16x4 pk;
#pragma unroll
          for (int e = 0; e < 4; ++e) {
            float p = __expf(s[ct][e] - m_r);
            rs += p;
            pk[e] = f2bf_native(p);
          }
          int slot = (ct * 2 + (l4 >> 1)) ^ (l15 & 7);
          *(u16x4*)&P[l15 * 64 + slot * 8 + (l4 & 1) * 4] = pk;
        }
        rs += __shfl_xor(rs, 16);
        rs += __shfl_xor(rs, 32);
        l_r += rs;

        __builtin_amdgcn_s_setprio(1);
#pragma unroll
        for (int kk = 0; kk < 2; ++kk) {
          bf16x8 pf = *(const bf16x8*)&P[l15 * 64 + (((kk * 4 + l4) ^ (l15 & 7)) * 8)];
#pragma unroll
          for (int cd = 0; cd < 4; ++cd) {
            int d = cd * 16 + l15;
            bf16x8 vf = *(const bf16x8*)&Vc[(d * 8 + ((kk * 4 + l4) ^ (d & 7))) * 8];
            o[cd] = MFMA16(pf, vf, o[cd]);
          }
        }
        __builtin_amdgcn_s_setprio(0);
      }

      // single drain+barrier per tile: prefetch loads land, all reads of cur done
      asm volatile("s_waitcnt vmcnt(0)" ::: "memory");
      __builtin_amdgcn_s_barrier();
      cur ^= 1;
    }

    // epilogue: divide by l (l for q-row r lives at lane r), store
    float rli = 1.0f / l_r;
#pragma unroll
    for (int cd = 0; cd < 4; ++cd)
#pragma unroll
      for (int e = 0; e < 4; ++e) {
        float rle = __shfl(rli, l4 * 4 + e);
        int r = l4 * 4 + e;
        int d = cd * 16 + l15;
        AO[(size_t)(b * 2048 + qw0 + r) * 2048 + h * 64 + d] = f2bf_native(o[cd][e] * rle);
      }
  }
}

// ---------------- launcher ----------------
extern "C" void kernel_launch(void* const* d_in, const int* in_sizes, int n_in,
                              void* d_out, int out_size, void* d_ws, size_t ws_size,
                              hipStream_t stream) {
  const float* X  = (const float*)d_in[0];
  const float* Wq = (const float*)d_in[1];
  const float* Wk = (const float*)d_in[2];
  const float* Wv = (const float*)d_in[3];
  const float* Wo = (const float*)d_in[4];
  float* out = (float*)d_out;

  u16* ws  = (u16*)d_ws;
  u16* Xb  = ws;                 // 8,388,608 elems  [4096][2048]
  u16* WqT = Xb  + 8388608;      // 4,194,304  [2048][2048] -- WqT,WkT,WvT contiguous [3072][2048]
  u16* WkT = WqT + 4194304;      // 1,048,576  [512][2048]
  u16* WvT = WkT + 1048576;      // 1,048,576  [512][2048]
  u16* WoT = WvT + 1048576;      // 4,194,304  [2048][2048]
  u16* Qb  = WoT + 4194304;      // 8,388,608  [4096][2048]  (pre-scaled by 0.125)
  u16* Kbf = Qb  + 8388608;      // 2,097,152  [4096][512]
  u16* VTb = Kbf + 2097152;      // 2,097,152  [512][4096]
  u16* AOb = Xb;                 // alias X after projections are done

  cvt_x<<<8192, 256, 0, stream>>>(X, Xb, 2097152);
  dim3 tb(32, 32);
  transpose_cvt<<<dim3(64, 64), tb, 0, stream>>>(Wq, WqT, 2048, 2048);
  transpose_cvt<<<dim3(16, 64), tb, 0, stream>>>(Wk, WkT, 2048, 512);
  transpose_cvt<<<dim3(16, 64), tb, 0, stream>>>(Wv, WvT, 2048, 512);
  transpose_cvt<<<dim3(64, 64), tb, 0, stream>>>(Wo, WoT, 2048, 2048);

  // fused QKV projection: BT = [WqT; WkT; WvT] (contiguous), N = 3072
  gemm_bt<4><<<dim3(24, 32), 256, 0, stream>>>(Xb, WqT, Qb, 4096, 3072, 2048);

  attn_fwd<<<dim3(32, 8, 2), 512, 0, stream>>>(Qb, Kbf, VTb, AOb);

  gemm_bt<2><<<dim3(16, 32), 256, 0, stream>>>(AOb, WoT, out, 4096, 2048, 2048);
}

// Round 6
// 225.541 us; speedup vs baseline: 2.4157x; 1.0214x over previous
//
#include <hip/hip_runtime.h>
#include <hip/hip_bf16.h>

typedef unsigned short u16;
typedef __bf16 bf16x8 __attribute__((ext_vector_type(8)));
typedef float f32x4 __attribute__((ext_vector_type(4)));
typedef unsigned short u16x4 __attribute__((ext_vector_type(4)));

#define MFMA16(a, b, c) __builtin_amdgcn_mfma_f32_16x16x32_bf16(a, b, c, 0, 0, 0)

__device__ __forceinline__ u16 f2bf(float f) {
  union { float f; unsigned u; } v; v.f = f;
  unsigned r = v.u + 0x7FFFu + ((v.u >> 16) & 1u);
  return (u16)(r >> 16);
}

__device__ __forceinline__ u16 f2bf_native(float f) {
  __hip_bfloat16 hb = __float2bfloat16(f);
  u16 out;
  __builtin_memcpy(&out, &hb, 2);
  return out;
}

__device__ __forceinline__ void gload16(const u16* g, u16* l) {
  __builtin_amdgcn_global_load_lds(
      (const __attribute__((address_space(1))) unsigned int*)g,
      (__attribute__((address_space(3))) unsigned int*)l, 16, 0, 0);
}

// ---------------- elementwise f32 -> bf16 ----------------
__global__ void cvt_x(const float* __restrict__ X, u16* __restrict__ Xb, int n4) {
  int i = blockIdx.x * blockDim.x + threadIdx.x;
  if (i < n4) {
    float4 v = ((const float4*)X)[i];
    u16x4 o = { f2bf(v.x), f2bf(v.y), f2bf(v.z), f2bf(v.w) };
    ((u16x4*)Xb)[i] = o;
  }
}

// ---------------- tiled transpose + convert: W[K][N] f32 -> WT[N][K] bf16 ----------------
__global__ void transpose_cvt(const float* __restrict__ W, u16* __restrict__ WT, int K, int N) {
  __shared__ float t[32][33];
  int n0 = blockIdx.x * 32, k0 = blockIdx.y * 32;
  int tx = threadIdx.x, ty = threadIdx.y;
  t[ty][tx] = W[(size_t)(k0 + ty) * N + n0 + tx];
  __syncthreads();
  WT[(size_t)(n0 + ty) * K + k0 + tx] = f2bf(t[tx][ty]);
}

// ---------------- 8-wave pipelined GEMM: C[M][N] = A[M][K] @ BT[N][K]^T ----------------
// BM=128, BN=256, BK=32. 512 threads = 8 waves (2M x 4N), wave tile 64x64, acc 4x4.
// T3-minimum schedule: STAGE(t+1) -> ds_read(t) -> MFMA -> vmcnt(0) -> s_barrier (1 barrier/tile).
// T1 XCD chunk swizzle on flattened block id (grids are %8==0).
// STORE: 2 = f32 row-major [M][N]
// STORE: 4 = fused QKV: bn<2048 -> Q bf16 *0.125 ; bn<2560 -> K bf16 ; else V transposed [512][4096]
__device__ __forceinline__ void stage_tile(const u16* __restrict__ A, const u16* __restrict__ BT,
                                           u16* la, u16* lb, int bm, int bn, int K, int k0, int tid) {
  {
    int arow = tid >> 2;
    int ac = (tid & 3) ^ ((arow >> 1) & 3);  // pre-swizzled global source (both-sides rule)
    gload16(A + (size_t)(bm + arow) * K + k0 + ac * 8, la + tid * 8);
  }
#pragma unroll
  for (int i = 0; i < 2; ++i) {
    int s = i * 512 + tid;
    int brow = s >> 2;
    int bc = (s & 3) ^ ((brow >> 1) & 3);
    gload16(BT + (size_t)(bn + brow) * K + k0 + bc * 8, lb + s * 8);
  }
}

template <int STORE>
__global__ __launch_bounds__(512) void gemm8(const u16* __restrict__ A,
                                             const u16* __restrict__ BT,
                                             void* __restrict__ Cv,
                                             int M, int N, int K) {
  __shared__ u16 lA[2][128 * 32];
  __shared__ u16 lB[2][256 * 32];
  const int tid = threadIdx.x;
  const int lane = tid & 63, wave = tid >> 6;
  const int gx = gridDim.x;
  const int nwg = gx * gridDim.y;
  const int bid = blockIdx.y * gx + blockIdx.x;
  const int sw = (bid & 7) * (nwg >> 3) + (bid >> 3);  // XCD chunk swizzle (nwg % 8 == 0)
  const int bx = sw % gx, by = sw / gx;
  const int bm = by * 128, bn = bx * 256;
  const int wm = (wave >> 2) * 64, wn = (wave & 3) * 64;
  const int l15 = lane & 15, l4 = lane >> 4;

  f32x4 acc[4][4] = {};

  u16* ra = (u16*)lA[0]; u16* rb = (u16*)lB[0];
  u16* wa = (u16*)lA[1]; u16* wb = (u16*)lB[1];

  // prologue: stage tile 0
  stage_tile(A, BT, ra, rb, bm, bn, K, 0, tid);
  asm volatile("s_waitcnt vmcnt(0)" ::: "memory");
  __builtin_amdgcn_s_barrier();

  const int NT = K >> 5;
#pragma unroll 1
  for (int t = 0; t < NT; ++t) {
    if (t + 1 < NT) stage_tile(A, BT, wa, wb, bm, bn, K, (t + 1) << 5, tid);
    bf16x8 af[4], bf[4];
#pragma unroll
    for (int i = 0; i < 4; ++i) {
      int r = wm + i * 16 + l15;
      af[i] = *(const bf16x8*)&ra[r * 32 + (l4 ^ ((r >> 1) & 3)) * 8];
      int n = wn + i * 16 + l15;
      bf[i] = *(const bf16x8*)&rb[n * 32 + (l4 ^ ((n >> 1) & 3)) * 8];
    }
    __builtin_amdgcn_s_setprio(1);
#pragma unroll
    for (int i = 0; i < 4; ++i)
#pragma unroll
      for (int j = 0; j < 4; ++j)
        acc[i][j] = MFMA16(af[i], bf[j], acc[i][j]);
    __builtin_amdgcn_s_setprio(0);
    asm volatile("s_waitcnt vmcnt(0)" ::: "memory");
    __builtin_amdgcn_s_barrier();
    u16* t1 = ra; ra = wa; wa = t1;
    u16* t2 = rb; rb = wb; wb = t2;
  }

#pragma unroll
  for (int i = 0; i < 4; ++i) {
    int row = bm + wm + i * 16 + l4 * 4;
#pragma unroll
    for (int j = 0; j < 4; ++j) {
      int col = bn + wn + j * 16 + l15;
#pragma unroll
      for (int e = 0; e < 4; ++e) {
        float v = acc[i][j][e];
        if (STORE == 2) {
          ((float*)Cv)[(size_t)(row + e) * N + col] = v;
        } else {  // STORE == 4, fused QKV
          u16* Qb = (u16*)Cv;
          u16* Kb = Qb + 8388608;
          u16* Vt = Kb + 2097152;
          if (col < 2048)       Qb[(size_t)(row + e) * 2048 + col] = f2bf(v * 0.125f);
          else if (col < 2560)  Kb[(size_t)(row + e) * 512 + (col - 2048)] = f2bf(v);
          else                  Vt[(size_t)(col - 2560) * 4096 + (row + e)] = f2bf(v);
        }
      }
    }
  }
}

// ---------------- causal flash attention, 8-wave blocks, swapped-QK softmax ----
// Q: [B*S][2048] bf16 pre-scaled by 0.125 (col = h*64+d), K: [B*S][512] bf16,
// VT: [512][B*S] bf16 (row = g*64+d), AO: [B*S][2048] bf16
// grid (32, G, B), block = 512 (8 waves = 4 heads x 2 q-subtiles of 16 rows).
// Block handles q-tiles {pair, 63-pair} sequentially -> uniform ~33 tiles/block.
// head h = a*8 + g attends group g (reference reshape mapping).
// Swapped QK^T: S = mfma(K, Q) -> lane holds column q = lane&15, rows t = ct*16 + l4*4 + e.
__global__ __launch_bounds__(512) void attn_fwd(const u16* __restrict__ Q,
                                                const u16* __restrict__ Kb,
                                                const u16* __restrict__ VT,
                                                u16* __restrict__ AO) {
  const int pair = blockIdx.x, g = blockIdx.y, b = blockIdx.z;
  const int tid = threadIdx.x;
  const int lane = tid & 63;
  const int wave = tid >> 6;
  const int a = wave >> 1;                  // head sub-index, h = a*8+g
  const int h = a * 8 + g;
  const int l15 = lane & 15, l4 = lane >> 4;

  __shared__ u16 Klds[2][64 * 64];   // [t][d], chunk-XOR swizzled
  __shared__ u16 Vlds[2][64 * 64];   // [d][t], chunk-XOR swizzled
  __shared__ u16 Plds[8][16 * 64];   // per-wave P, [q][t], 16B-slot XOR swizzled

  // staging coords: slot = tid, row = tid>>3, chunk c = tid&7, src chunk swizzled
  const int srow = tid >> 3, sc = (tid & 7) ^ (srow & 7);

  int cur = 0;
#pragma unroll 1
  for (int pass = 0; pass < 2; ++pass) {
    const int qt = (pass == 0) ? pair : 63 - pair;
    const int qw0 = qt * 32 + (wave & 1) * 16;  // this wave's first q row
    const int nt = qt / 2 + 1;                  // K/V tiles for this q-tile

    const u16* qp = Q + (size_t)(b * 2048 + qw0 + l15) * 2048 + h * 64 + l4 * 8;
    bf16x8 qf0 = *(const bf16x8*)qp;
    bf16x8 qf1 = *(const bf16x8*)(qp + 32);

    float m_r = -1e30f, l_r = 0.f;
    f32x4 o[4] = {};

    // prologue: stage tile 0
    {
      gload16(Kb + (size_t)(b * 2048 + 0 + srow) * 512 + g * 64 + sc * 8, &Klds[cur][tid * 8]);
      gload16(VT + (size_t)(g * 64 + srow) * 4096 + b * 2048 + 0 + sc * 8, &Vlds[cur][tid * 8]);
      asm volatile("s_waitcnt vmcnt(0)" ::: "memory");
      __builtin_amdgcn_s_barrier();
    }

#pragma unroll 1
    for (int ti = 0; ti < nt; ++ti) {
      const int t0 = ti * 64;
      // issue prefetch of next tile into the other buffer
      if (ti + 1 < nt) {
        const int tn = t0 + 64;
        gload16(Kb + (size_t)(b * 2048 + tn + srow) * 512 + g * 64 + sc * 8, &Klds[cur ^ 1][tid * 8]);
        gload16(VT + (size_t)(g * 64 + srow) * 4096 + b * 2048 + tn + sc * 8, &Vlds[cur ^ 1][tid * 8]);
      }

      if (t0 <= qw0 + 15) {  // wave has at least one unmasked row in this tile
        const u16* Kc = Klds[cur];
        const u16* Vc = Vlds[cur];
        f32x4 s[4];
        __builtin_amdgcn_s_setprio(1);
#pragma unroll
        for (int ct = 0; ct < 4; ++ct) {
          int t = ct * 16 + l15;
          bf16x8 kf0 = *(const bf16x8*)&Kc[(t * 8 + (l4 ^ (t & 7))) * 8];
          bf16x8 kf1 = *(const bf16x8*)&Kc[(t * 8 + ((l4 + 4) ^ (t & 7))) * 8];
          f32x4 sv = {0.f, 0.f, 0.f, 0.f};
          sv = MFMA16(kf0, qf0, sv);   // swapped: S[t][q]
          sv = MFMA16(kf1, qf1, sv);
          s[ct] = sv;
        }
        __builtin_amdgcn_s_setprio(0);

        // causal mask (Q pre-scaled; no scale here). lane's q = qw0+l15, t = t0+ct*16+l4*4+e
        if (t0 + 63 > qw0) {
          const int qg = qw0 + l15;
#pragma unroll
          for (int ct = 0; ct < 4; ++ct)
#pragma unroll
            for (int e = 0; e < 4; ++e) {
              int tg = t0 + ct * 16 + l4 * 4 + e;
              if (tg > qg) s[ct][e] = -1e30f;
            }
        }

        // in-lane max over 16 values, then cross-l4 reduce (2 shfl)
        float m0 = fmaxf(fmaxf(s[0][0], s[0][1]), fmaxf(s[0][2], s[0][3]));
        float m1 = fmaxf(fmaxf(s[1][0], s[1][1]), fmaxf(s[1][2], s[1][3]));
        float m2 = fmaxf(fmaxf(s[2][0], s[2][1]), fmaxf(s[2][2], s[2][3]));
        float m3 = fmaxf(fmaxf(s[3][0], s[3][1]), fmaxf(s[3][2], s[3][3]));
        float mt = fmaxf(fmaxf(m0, m1), fmaxf(m2, m3));
        mt = fmaxf(mt, __shfl_xor(mt, 16));
        mt = fmaxf(mt, __shfl_xor(mt, 32));

        // defer-max (T13): skip rescale when max growth small
        if (!__all(mt <= m_r + 8.0f)) {
          float mn = fmaxf(m_r, mt);
          float alpha = __expf(m_r - mn);
          m_r = mn;
          l_r *= alpha;
#pragma unroll
          for (int e = 0; e < 4; ++e) {
            float ae = __shfl(alpha, l4 * 4 + e);  // alpha for q-row l4*4+e lives at lane l4*4+e
            o[0][e] *= ae; o[1][e] *= ae; o[2][e] *= ae; o[3][e] *= ae;
          }
        }

        // exp + sum + pack + P-write (4x ds_write_b64, 16B-slot swizzle)
        u16* P = Plds[wave];
        float rs = 0.f;
#pragma unroll
        for (int ct = 0; ct < 4; ++ct) {
          u16x4 pk;
#pragma unroll
          for (int e = 0; e < 4; ++e) {
            float p = __expf(s[ct][e] - m_r);
            rs += p;
            pk[e] = f2bf_native(p);
          }
          int slot = (ct * 2 + (l4 >> 1)) ^ (l15 & 7);
          *(u16x4*)&P[l15 * 64 + slot * 8 + (l4 & 1) * 4] = pk;
        }
        rs += __shfl_xor(rs, 16);
        rs += __shfl_xor(rs, 32);
        l_r += rs;

        __builtin_amdgcn_s_setprio(1);
#pragma unroll
        for (int kk = 0; kk < 2; ++kk) {
          bf16x8 pf = *(const bf16x8*)&P[l15 * 64 + (((kk * 4 + l4) ^ (l15 & 7)) * 8)];
#pragma unroll
          for (int cd = 0; cd < 4; ++cd) {
            int d = cd * 16 + l15;
            bf16x8 vf = *(const bf16x8*)&Vc[(d * 8 + ((kk * 4 + l4) ^ (d & 7))) * 8];
            o[cd] = MFMA16(pf, vf, o[cd]);
          }
        }
        __builtin_amdgcn_s_setprio(0);
      }

      // single drain+barrier per tile: prefetch loads land, all reads of cur done
      asm volatile("s_waitcnt vmcnt(0)" ::: "memory");
      __builtin_amdgcn_s_barrier();
      cur ^= 1;
    }

    // epilogue: divide by l (l for q-row r lives at lane r), store
    float rli = 1.0f / l_r;
#pragma unroll
    for (int cd = 0; cd < 4; ++cd)
#pragma unroll
      for (int e = 0; e < 4; ++e) {
        float rle = __shfl(rli, l4 * 4 + e);
        int r = l4 * 4 + e;
        int d = cd * 16 + l15;
        AO[(size_t)(b * 2048 + qw0 + r) * 2048 + h * 64 + d] = f2bf_native(o[cd][e] * rle);
      }
  }
}

// ---------------- launcher ----------------
extern "C" void kernel_launch(void* const* d_in, const int* in_sizes, int n_in,
                              void* d_out, int out_size, void* d_ws, size_t ws_size,
                              hipStream_t stream) {
  const float* X  = (const float*)d_in[0];
  const float* Wq = (const float*)d_in[1];
  const float* Wk = (const float*)d_in[2];
  const float* Wv = (const float*)d_in[3];
  const float* Wo = (const float*)d_in[4];
  float* out = (float*)d_out;

  u16* ws  = (u16*)d_ws;
  u16* Xb  = ws;                 // 8,388,608 elems  [4096][2048]
  u16* WqT = Xb  + 8388608;      // 4,194,304  [2048][2048] -- WqT,WkT,WvT contiguous [3072][2048]
  u16* WkT = WqT + 4194304;      // 1,048,576  [512][2048]
  u16* WvT = WkT + 1048576;      // 1,048,576  [512][2048]
  u16* WoT = WvT + 1048576;      // 4,194,304  [2048][2048]
  u16* Qb  = WoT + 4194304;      // 8,388,608  [4096][2048]  (pre-scaled by 0.125)
  u16* Kbf = Qb  + 8388608;      // 2,097,152  [4096][512]
  u16* VTb = Kbf + 2097152;      // 2,097,152  [512][4096]
  u16* AOb = Xb;                 // alias X after projections are done

  cvt_x<<<8192, 256, 0, stream>>>(X, Xb, 2097152);
  dim3 tb(32, 32);
  transpose_cvt<<<dim3(64, 64), tb, 0, stream>>>(Wq, WqT, 2048, 2048);
  transpose_cvt<<<dim3(16, 64), tb, 0, stream>>>(Wk, WkT, 2048, 512);
  transpose_cvt<<<dim3(16, 64), tb, 0, stream>>>(Wv, WvT, 2048, 512);
  transpose_cvt<<<dim3(64, 64), tb, 0, stream>>>(Wo, WoT, 2048, 2048);

  // fused QKV projection: BT = [WqT; WkT; WvT] (contiguous), N = 3072, grid 12x32 = 384 blocks
  gemm8<4><<<dim3(12, 32), 512, 0, stream>>>(Xb, WqT, Qb, 4096, 3072, 2048);

  attn_fwd<<<dim3(32, 8, 2), 512, 0, stream>>>(Qb, Kbf, VTb, AOb);

  // output projection: grid 8x32 = 256 blocks
  gemm8<2><<<dim3(8, 32), 512, 0, stream>>>(AOb, WoT, out, 4096, 2048, 2048);
}